// Round 4
// baseline (2975.359 us; speedup 1.0000x reference)
//
#include <hip/hip_runtime.h>
#include <cstdint>

typedef float f4 __attribute__((ext_vector_type(4)));
typedef float f2 __attribute__((ext_vector_type(2)));

__device__ inline f4 f4_zero(){ f4 v = {0.f,0.f,0.f,0.f}; return v; }

#define PB 256   // blocks for hist/scatter; each (block,bucket) owns a private output range

// ---------- detect int64 vs int32 edge_index ----------
__global__ void k_detect(const uint32_t* __restrict__ p, int* __restrict__ flag){
    __shared__ int nz;
    if (threadIdx.x == 0) nz = 0;
    __syncthreads();
    int local = 0;
    for (int i = threadIdx.x; i < 2048; i += blockDim.x)
        if (p[2*i + 1] != 0u) local = 1;
    if (local) atomicOr(&nz, 1);
    __syncthreads();
    if (threadIdx.x == 0) *flag = (nz == 0) ? 1 : 0;   // 1 => int64
}

// ---------- per-block coarse histogram (bucket = dst>>7) ----------
__global__ __launch_bounds__(1024) void k_hist(const void* __restrict__ eidx, int E, int NB,
                                               const int* __restrict__ flag,
                                               int* __restrict__ blkhist){
    __shared__ int lh[1024];
    int t = threadIdx.x, blk = blockIdx.x;
    for (int i = t; i < NB; i += 1024) lh[i] = 0;
    __syncthreads();
    int R = (E + PB - 1) / PB;
    int s = blk * R, e_end = s + R < E ? s + R : E;
    bool is64 = (*flag != 0);
    const uint32_t* p32 = (const uint32_t*)eidx;
    const int*      pi  = (const int*)eidx;
    for (int e = s + t; e < e_end; e += 1024){
        int d = is64 ? (int)p32[2*(size_t)(E + e)] : pi[(size_t)E + e];
        atomicAdd(&lh[d >> 7], 1);
    }
    __syncthreads();
    for (int i = t; i < NB; i += 1024)
        blkhist[(size_t)i * PB + blk] = lh[i];      // block-private slot, no atomic
}

// ---------- per-bucket totals ----------
__global__ __launch_bounds__(PB) void k_btot(const int* __restrict__ blkhist,
                                             int* __restrict__ tot){
    int b = blockIdx.x, t = threadIdx.x, lane = t & 63, w = t >> 6;
    int v = blkhist[(size_t)b * PB + t];
    #pragma unroll
    for (int off = 32; off; off >>= 1) v += __shfl_down(v, off, 64);
    __shared__ int ws[4];
    if (lane == 0) ws[w] = v;
    __syncthreads();
    if (t == 0) tot[b] = ws[0] + ws[1] + ws[2] + ws[3];
}

// ---------- exclusive scan of bucket totals (NB <= 1024) ----------
__global__ __launch_bounds__(1024) void k_bscan(const int* __restrict__ tot, int n,
                                                int* __restrict__ coff){
    int t = threadIdx.x, lane = t & 63, w = t >> 6;
    int v = (t < n) ? tot[t] : 0;
    int x = v;
    #pragma unroll
    for (int off = 1; off < 64; off <<= 1){
        int u = __shfl_up(x, off, 64);
        if (lane >= off) x += u;
    }
    __shared__ int ws[16];
    if (lane == 63) ws[w] = x;
    __syncthreads();
    if (w == 0 && lane < 16){
        int y = ws[lane];
        #pragma unroll
        for (int off = 1; off < 16; off <<= 1){
            int u = __shfl_up(y, off, 64);
            if (lane >= off) y += u;
        }
        ws[lane] = y;
    }
    __syncthreads();
    int incl = x + (w ? ws[w - 1] : 0);
    if (t < n)     coff[t] = incl - v;
    if (t == n - 1) coff[n] = incl;     // == E
}

// ---------- per-(bucket,block) offsets ----------
__global__ __launch_bounds__(PB) void k_boff(const int* __restrict__ blkhist,
                                             const int* __restrict__ coff,
                                             int* __restrict__ offs){
    int b = blockIdx.x, t = threadIdx.x, lane = t & 63, w = t >> 6;
    int h = blkhist[(size_t)b * PB + t];
    int x = h;
    #pragma unroll
    for (int off = 1; off < 64; off <<= 1){
        int u = __shfl_up(x, off, 64);
        if (lane >= off) x += u;
    }
    __shared__ int ws[4];
    if (lane == 63) ws[w] = x;
    __syncthreads();
    int add = 0;
    for (int j = 0; j < w; ++j) add += ws[j];
    offs[(size_t)b * PB + t] = coff[b] + add + x - h;   // exclusive within bucket
}

// ---------- scatter edges into coarse buckets (packed (dst&127)<<17 | src) ----------
__global__ __launch_bounds__(1024) void k_scatter(const void* __restrict__ eidx, int E, int NB,
                                                  const int* __restrict__ flag,
                                                  const int* __restrict__ offs,
                                                  uint32_t* __restrict__ bucketed){
    __shared__ int cur[1024];
    int t = threadIdx.x, blk = blockIdx.x;
    for (int i = t; i < NB; i += 1024) cur[i] = offs[(size_t)i * PB + blk];
    __syncthreads();
    int R = (E + PB - 1) / PB;
    int s = blk * R, e_end = s + R < E ? s + R : E;
    bool is64 = (*flag != 0);
    const uint32_t* p32 = (const uint32_t*)eidx;
    const int*      pi  = (const int*)eidx;
    for (int e = s + t; e < e_end; e += 1024){
        int sv, dv;
        if (is64){ sv = (int)p32[2*(size_t)e]; dv = (int)p32[2*(size_t)(E + e)]; }
        else     { sv = pi[e];                 dv = pi[(size_t)E + e]; }
        int b = dv >> 7;
        int pos = atomicAdd(&cur[b], 1);      // LDS atomic; global range block-private
        bucketed[pos] = ((uint32_t)(dv & 127) << 17) | (uint32_t)sv;
    }
}

// ---------- bucketed mean aggregation: 1 block per 128-node bucket ----------
// One edge per wave-instruction: lane l owns floats [2l, 2l+1] of the row.
// Gather = 512B fully-coalesced per edge. Accumulate via 2 LDS f32 atomics/edge
// into a 129-padded accumulator: bank = (129*dlow + 2l + j) % 32 -> 16 banks,
// ~4-way conflict (vs 8-way on the unpadded f4 scheme).
__global__ __launch_bounds__(1024) void k_bucket_agg(const float* __restrict__ feat,
                                                     const uint32_t* __restrict__ bucketed,
                                                     const int* __restrict__ coff,
                                                     float* __restrict__ agg, int N){
    __shared__ float acc[128][129];   // 64.5 KB, padded stride vs bank conflicts
    __shared__ int   cnt[128];
    int t = threadIdx.x, b = blockIdx.x;
    for (int i = t; i < 128*129; i += 1024) ((float*)acc)[i] = 0.f;
    if (t < 128) cnt[t] = 0;
    __syncthreads();
    int s = coff[b], e_end = coff[b + 1];
    int w = t >> 6, lane = t & 63;
    // wave w processes edge pairs (s+2p, s+2p+1), p = w, w+16, w+32, ...
    for (int p = w; ; p += 16){
        int e0 = s + 2*p;
        if (e0 >= e_end) break;
        uint32_t v0 = bucketed[e0];
        bool has1 = (e0 + 1 < e_end);
        uint32_t v1 = has1 ? bucketed[e0 + 1] : v0;
        int d0 = (int)((v0 >> 17) & 127u), s0 = (int)(v0 & 0x1FFFFu);
        int d1 = (int)((v1 >> 17) & 127u), s1 = (int)(v1 & 0x1FFFFu);
        f2 g0 = *((const f2*)(feat + (size_t)s0 * 128 + 2*lane));
        f2 g1 = *((const f2*)(feat + (size_t)s1 * 128 + 2*lane));
        atomicAdd(&acc[d0][2*lane + 0], g0[0]);
        atomicAdd(&acc[d0][2*lane + 1], g0[1]);
        if (lane == 0) atomicAdd(&cnt[d0], 1);
        if (has1){
            atomicAdd(&acc[d1][2*lane + 0], g1[0]);
            atomicAdd(&acc[d1][2*lane + 1], g1[1]);
            if (lane == 0) atomicAdd(&cnt[d1], 1);
        }
    }
    __syncthreads();
    int node0 = b * 128;
    for (int i = t; i < 128*32; i += 1024){
        int r = i >> 5, c4 = i & 31;
        int node = node0 + r;
        if (node < N){
            int deg = cnt[r];
            float scl = 1.0f / (float)(deg > 1 ? deg : 1);
            f4 v;
            v[0] = acc[r][4*c4 + 0]; v[1] = acc[r][4*c4 + 1];
            v[2] = acc[r][4*c4 + 2]; v[3] = acc[r][4*c4 + 3];
            ((f4*)agg)[(size_t)node * 32 + c4] = v * scl;
        }
    }
}

// ---------- fused SAGE linear: out = relu(agg@Wl + bl + X@Wr) ----------
// One K=256 GEMM: A = [agg | X], B = [Wl ; Wr]. 64x128 tile, 8x4 acc/thread.
// out may alias A2: blocks read only their own 64 A2 rows, all before epilogue.
__global__ __launch_bounds__(256) void k_sage_gemm(
    const float* __restrict__ A1, const float* __restrict__ A2,
    const float* __restrict__ Wl, const float* __restrict__ Wr,
    const float* __restrict__ bias, float* __restrict__ out, int M)
{
    __shared__ __attribute__((aligned(16))) float Bs[64][128];
    __shared__ __attribute__((aligned(16))) float As[64][64];   // [k][row]
    int tid = threadIdx.x;
    int tx  = tid & 31;
    int ty  = tid >> 5;
    int row0 = blockIdx.x * 64;

    float acc[8][4];
    #pragma unroll
    for (int i = 0; i < 8; ++i)
        #pragma unroll
        for (int j = 0; j < 4; ++j) acc[i][j] = 0.f;

    for (int ch = 0; ch < 4; ++ch){
        const float* Asrc = (ch < 2) ? A1 : A2;
        const float* Bsrc = (ch < 2) ? Wl : Wr;
        int kOff = (ch & 1) * 64;
        #pragma unroll
        for (int j = 0; j < 8; ++j){
            int f = tid + j * 256;
            int k = f >> 5, c4 = f & 31;
            f4 v = ((const f4*)Bsrc)[(size_t)(kOff + k) * 32 + c4];
            *((f4*)&Bs[k][c4 * 4]) = v;
        }
        #pragma unroll
        for (int j = 0; j < 4; ++j){
            int f = tid + j * 256;
            int r = f & 63, kq = f >> 6;
            f4 v = f4_zero();
            if (row0 + r < M)
                v = ((const f4*)Asrc)[(size_t)(row0 + r) * 32 + (kOff >> 2) + kq];
            As[kq * 4 + 0][r] = v[0];
            As[kq * 4 + 1][r] = v[1];
            As[kq * 4 + 2][r] = v[2];
            As[kq * 4 + 3][r] = v[3];
        }
        __syncthreads();
        #pragma unroll 4
        for (int k = 0; k < 64; ++k){
            f4 b  = *((const f4*)&Bs[k][tx * 4]);
            f4 a0 = *((const f4*)&As[k][ty * 8]);
            f4 a1 = *((const f4*)&As[k][ty * 8 + 4]);
            #pragma unroll
            for (int i = 0; i < 4; ++i){
                #pragma unroll
                for (int j = 0; j < 4; ++j){
                    acc[i][j]     += a0[i] * b[j];
                    acc[i + 4][j] += a1[i] * b[j];
                }
            }
        }
        __syncthreads();
    }
    f4 bb = ((const f4*)bias)[tx];
    #pragma unroll
    for (int i = 0; i < 8; ++i){
        int r = row0 + ty * 8 + i;
        if (r < M){
            f4 v;
            #pragma unroll
            for (int j = 0; j < 4; ++j){
                float tmp = acc[i][j] + bb[j];
                v[j] = tmp > 0.f ? tmp : 0.f;
            }
            ((f4*)out)[(size_t)r * 32 + tx] = v;
        }
    }
}

extern "C" void kernel_launch(void* const* d_in, const int* in_sizes, int n_in,
                              void* d_out, int out_size, void* d_ws, size_t ws_size,
                              hipStream_t stream) {
    const float* x    = (const float*)d_in[0];
    const float* Wl1  = (const float*)d_in[1];
    const float* bl1  = (const float*)d_in[2];
    const float* Wr1  = (const float*)d_in[3];
    const float* Wl2  = (const float*)d_in[4];
    const float* bl2  = (const float*)d_in[5];
    const float* Wr2  = (const float*)d_in[6];
    const void*  eidx = d_in[7];
    float* out = (float*)d_out;

    const int N  = in_sizes[0] / 128;
    const int E  = in_sizes[7] / 2;
    const int NB = (N + 127) >> 7;          // 128-node coarse buckets (<=1024)

    char* ws = (char*)d_ws;
    size_t off = 0;
    auto alloc = [&](size_t bytes) -> void* {
        void* p = ws + off;
        off += (bytes + 255) & ~(size_t)255;
        return p;
    };
    int*      flag     = (int*)     alloc(4);
    int*      blkhist  = (int*)     alloc((size_t)NB * PB * 4);
    int*      tot      = (int*)     alloc((size_t)NB * 4);
    int*      coff     = (int*)     alloc((size_t)(NB + 1) * 4);
    int*      offs     = (int*)     alloc((size_t)NB * PB * 4);
    uint32_t* bucketed = (uint32_t*)alloc((size_t)E * 4);
    float*    agg      = (float*)   alloc((size_t)N * 128 * 4);
    float*    h        = out;       // layer-1 output aliases d_out (safe, see gemm)

    // ---- build coarse-bucketed edge list (once, reused by both layers) ----
    k_detect <<<1, 256, 0, stream>>>((const uint32_t*)eidx, flag);
    k_hist   <<<PB, 1024, 0, stream>>>(eidx, E, NB, flag, blkhist);
    k_btot   <<<NB, PB,   0, stream>>>(blkhist, tot);
    k_bscan  <<<1, 1024,  0, stream>>>(tot, NB, coff);
    k_boff   <<<NB, PB,   0, stream>>>(blkhist, coff, offs);
    k_scatter<<<PB, 1024, 0, stream>>>(eidx, E, NB, flag, offs, bucketed);

    // ---- layer 1: h = relu(mean_agg(x) @ Wl1 + bl1 + x @ Wr1) ----
    k_bucket_agg<<<NB, 1024, 0, stream>>>(x, bucketed, coff, agg, N);
    k_sage_gemm <<<(N + 63) / 64, 256, 0, stream>>>(agg, x, Wl1, Wr1, bl1, h, N);

    // ---- layer 2: out = relu(mean_agg(h) @ Wl2 + bl2 + h @ Wr2) ----
    k_bucket_agg<<<NB, 1024, 0, stream>>>(h, bucketed, coff, agg, N);
    k_sage_gemm <<<(N + 63) / 64, 256, 0, stream>>>(agg, h, Wl2, Wr2, bl2, out, N);
}

// Round 5
// 554.427 us; speedup vs baseline: 5.3665x; 5.3665x over previous
//
#include <hip/hip_runtime.h>
#include <cstdint>

typedef float f4 __attribute__((ext_vector_type(4)));
typedef float f2 __attribute__((ext_vector_type(2)));

__device__ inline f4 f4_zero(){ f4 v = {0.f,0.f,0.f,0.f}; return v; }

#define PB 256   // blocks for hist/scatter; each (block,bucket) owns a private output range

// ---------- detect int64 vs int32 edge_index ----------
__global__ void k_detect(const uint32_t* __restrict__ p, int* __restrict__ flag){
    __shared__ int nz;
    if (threadIdx.x == 0) nz = 0;
    __syncthreads();
    int local = 0;
    for (int i = threadIdx.x; i < 2048; i += blockDim.x)
        if (p[2*i + 1] != 0u) local = 1;
    if (local) atomicOr(&nz, 1);
    __syncthreads();
    if (threadIdx.x == 0) *flag = (nz == 0) ? 1 : 0;   // 1 => int64
}

// ---------- per-block coarse histogram (bucket = dst>>7) ----------
__global__ __launch_bounds__(1024) void k_hist(const void* __restrict__ eidx, int E, int NB,
                                               const int* __restrict__ flag,
                                               int* __restrict__ blkhist){
    __shared__ int lh[1024];
    int t = threadIdx.x, blk = blockIdx.x;
    for (int i = t; i < NB; i += 1024) lh[i] = 0;
    __syncthreads();
    int R = (E + PB - 1) / PB;
    int s = blk * R, e_end = s + R < E ? s + R : E;
    bool is64 = (*flag != 0);
    const uint32_t* p32 = (const uint32_t*)eidx;
    const int*      pi  = (const int*)eidx;
    for (int e = s + t; e < e_end; e += 1024){
        int d = is64 ? (int)p32[2*(size_t)(E + e)] : pi[(size_t)E + e];
        atomicAdd(&lh[d >> 7], 1);
    }
    __syncthreads();
    for (int i = t; i < NB; i += 1024)
        blkhist[(size_t)i * PB + blk] = lh[i];      // block-private slot, no atomic
}

// ---------- per-bucket totals ----------
__global__ __launch_bounds__(PB) void k_btot(const int* __restrict__ blkhist,
                                             int* __restrict__ tot){
    int b = blockIdx.x, t = threadIdx.x, lane = t & 63, w = t >> 6;
    int v = blkhist[(size_t)b * PB + t];
    #pragma unroll
    for (int off = 32; off; off >>= 1) v += __shfl_down(v, off, 64);
    __shared__ int ws[4];
    if (lane == 0) ws[w] = v;
    __syncthreads();
    if (t == 0) tot[b] = ws[0] + ws[1] + ws[2] + ws[3];
}

// ---------- exclusive scan of bucket totals (NB <= 1024) ----------
__global__ __launch_bounds__(1024) void k_bscan(const int* __restrict__ tot, int n,
                                                int* __restrict__ coff){
    int t = threadIdx.x, lane = t & 63, w = t >> 6;
    int v = (t < n) ? tot[t] : 0;
    int x = v;
    #pragma unroll
    for (int off = 1; off < 64; off <<= 1){
        int u = __shfl_up(x, off, 64);
        if (lane >= off) x += u;
    }
    __shared__ int ws[16];
    if (lane == 63) ws[w] = x;
    __syncthreads();
    if (w == 0 && lane < 16){
        int y = ws[lane];
        #pragma unroll
        for (int off = 1; off < 16; off <<= 1){
            int u = __shfl_up(y, off, 64);
            if (lane >= off) y += u;
        }
        ws[lane] = y;
    }
    __syncthreads();
    int incl = x + (w ? ws[w - 1] : 0);
    if (t < n)     coff[t] = incl - v;
    if (t == n - 1) coff[n] = incl;     // == E
}

// ---------- per-(bucket,block) offsets ----------
__global__ __launch_bounds__(PB) void k_boff(const int* __restrict__ blkhist,
                                             const int* __restrict__ coff,
                                             int* __restrict__ offs){
    int b = blockIdx.x, t = threadIdx.x, lane = t & 63, w = t >> 6;
    int h = blkhist[(size_t)b * PB + t];
    int x = h;
    #pragma unroll
    for (int off = 1; off < 64; off <<= 1){
        int u = __shfl_up(x, off, 64);
        if (lane >= off) x += u;
    }
    __shared__ int ws[4];
    if (lane == 63) ws[w] = x;
    __syncthreads();
    int add = 0;
    for (int j = 0; j < w; ++j) add += ws[j];
    offs[(size_t)b * PB + t] = coff[b] + add + x - h;   // exclusive within bucket
}

// ---------- scatter edges into coarse buckets (packed (dst&127)<<17 | src) ----------
__global__ __launch_bounds__(1024) void k_scatter(const void* __restrict__ eidx, int E, int NB,
                                                  const int* __restrict__ flag,
                                                  const int* __restrict__ offs,
                                                  uint32_t* __restrict__ bucketed){
    __shared__ int cur[1024];
    int t = threadIdx.x, blk = blockIdx.x;
    for (int i = t; i < NB; i += 1024) cur[i] = offs[(size_t)i * PB + blk];
    __syncthreads();
    int R = (E + PB - 1) / PB;
    int s = blk * R, e_end = s + R < E ? s + R : E;
    bool is64 = (*flag != 0);
    const uint32_t* p32 = (const uint32_t*)eidx;
    const int*      pi  = (const int*)eidx;
    for (int e = s + t; e < e_end; e += 1024){
        int sv, dv;
        if (is64){ sv = (int)p32[2*(size_t)e]; dv = (int)p32[2*(size_t)(E + e)]; }
        else     { sv = pi[e];                 dv = pi[(size_t)E + e]; }
        int b = dv >> 7;
        int pos = atomicAdd(&cur[b], 1);      // LDS atomic; global range block-private
        bucketed[pos] = ((uint32_t)(dv & 127) << 17) | (uint32_t)sv;
    }
}

// ---------- per-bucket counting sort -> full dst-sorted CSR ----------
// One block per 128-node bucket: LDS hist of dlow, 128-wide scan, scatter
// src into esrc (contiguous 8KB range per bucket) + write rowptr.
__global__ __launch_bounds__(1024) void k_bucketsort(const uint32_t* __restrict__ bucketed,
                                                     const int* __restrict__ coff,
                                                     int* __restrict__ esrc,
                                                     int* __restrict__ rowptr,
                                                     int N, int E, int NB){
    __shared__ int hist[128], cur[128], wtot[2];
    int b = blockIdx.x, t = threadIdx.x;
    if (t < 128) hist[t] = 0;
    __syncthreads();
    int s = coff[b], e_end = coff[b + 1];
    for (int i = s + t; i < e_end; i += 1024)
        atomicAdd(&hist[bucketed[i] >> 17], 1);
    __syncthreads();
    int x = 0, v = 0;
    if (t < 128){
        int lane = t & 63;
        v = hist[t]; x = v;
        #pragma unroll
        for (int off = 1; off < 64; off <<= 1){
            int u = __shfl_up(x, off, 64);
            if (lane >= off) x += u;
        }
        if (lane == 63) wtot[t >> 6] = x;
    }
    __syncthreads();
    if (t < 128){
        int w = t >> 6;
        int excl = x - v + (w ? wtot[0] : 0);     // exclusive within bucket
        int abs0 = s + excl;
        cur[t] = abs0;
        int node = b * 128 + t;
        if (node < N) rowptr[node] = abs0;
    }
    if (b == NB - 1 && t == 0) rowptr[N] = E;
    __syncthreads();
    for (int i = s + t; i < e_end; i += 1024){
        uint32_t val = bucketed[i];
        int r = (int)(val >> 17);
        int pos = atomicAdd(&cur[r], 1);
        esrc[pos] = (int)(val & 0x1FFFFu);
    }
}

// ---------- mean aggregation: one wave per dst node, register accumulation ----
// Edge indices fetched 64-at-a-time via a per-lane VECTOR load (not the scalar
// path!), broadcast with __shfl; 4 independent gather chains per wave for MLP.
__global__ __launch_bounds__(256) void k_aggregate(const float* __restrict__ feat,
                                                   const int* __restrict__ rowptr,
                                                   const int* __restrict__ esrc,
                                                   float* __restrict__ agg, int N){
    int node = blockIdx.x * 4 + (threadIdx.x >> 6);
    if (node >= N) return;
    int lane = threadIdx.x & 63;
    int b = rowptr[node], e = rowptr[node + 1];
    const f2* feat2 = (const f2*)feat;
    f2 a0 = {0.f,0.f}, a1 = {0.f,0.f}, a2 = {0.f,0.f}, a3 = {0.f,0.f};
    for (int base = b; base < e; base += 64){
        int m = e - base; if (m > 64) m = 64;
        int idx = (lane < m) ? esrc[base + lane] : 0;   // vector load, 256B/wave
        int j = 0;
        for (; j + 4 <= m; j += 4){
            int s0 = __shfl(idx, j,     64);
            int s1 = __shfl(idx, j + 1, 64);
            int s2 = __shfl(idx, j + 2, 64);
            int s3 = __shfl(idx, j + 3, 64);
            a0 += feat2[(size_t)s0 * 64 + lane];
            a1 += feat2[(size_t)s1 * 64 + lane];
            a2 += feat2[(size_t)s2 * 64 + lane];
            a3 += feat2[(size_t)s3 * 64 + lane];
        }
        for (; j < m; ++j){
            int s0 = __shfl(idx, j, 64);
            a0 += feat2[(size_t)s0 * 64 + lane];
        }
    }
    f2 acc = (a0 + a1) + (a2 + a3);
    int deg = e - b;
    float scl = 1.0f / (float)(deg > 1 ? deg : 1);
    ((f2*)agg)[(size_t)node * 64 + lane] = acc * scl;
}

// ---------- fused SAGE linear: out = relu(agg@Wl + bl + X@Wr) ----------
// One K=256 GEMM: A = [agg | X], B = [Wl ; Wr]. 64x128 tile, 8x4 acc/thread.
// out may alias A2: blocks read only their own 64 A2 rows, all before epilogue.
__global__ __launch_bounds__(256) void k_sage_gemm(
    const float* __restrict__ A1, const float* __restrict__ A2,
    const float* __restrict__ Wl, const float* __restrict__ Wr,
    const float* __restrict__ bias, float* __restrict__ out, int M)
{
    __shared__ __attribute__((aligned(16))) float Bs[64][128];
    __shared__ __attribute__((aligned(16))) float As[64][64];   // [k][row]
    int tid = threadIdx.x;
    int tx  = tid & 31;
    int ty  = tid >> 5;
    int row0 = blockIdx.x * 64;

    float acc[8][4];
    #pragma unroll
    for (int i = 0; i < 8; ++i)
        #pragma unroll
        for (int j = 0; j < 4; ++j) acc[i][j] = 0.f;

    for (int ch = 0; ch < 4; ++ch){
        const float* Asrc = (ch < 2) ? A1 : A2;
        const float* Bsrc = (ch < 2) ? Wl : Wr;
        int kOff = (ch & 1) * 64;
        #pragma unroll
        for (int j = 0; j < 8; ++j){
            int f = tid + j * 256;
            int k = f >> 5, c4 = f & 31;
            f4 v = ((const f4*)Bsrc)[(size_t)(kOff + k) * 32 + c4];
            *((f4*)&Bs[k][c4 * 4]) = v;
        }
        #pragma unroll
        for (int j = 0; j < 4; ++j){
            int f = tid + j * 256;
            int r = f & 63, kq = f >> 6;
            f4 v = f4_zero();
            if (row0 + r < M)
                v = ((const f4*)Asrc)[(size_t)(row0 + r) * 32 + (kOff >> 2) + kq];
            As[kq * 4 + 0][r] = v[0];
            As[kq * 4 + 1][r] = v[1];
            As[kq * 4 + 2][r] = v[2];
            As[kq * 4 + 3][r] = v[3];
        }
        __syncthreads();
        #pragma unroll 4
        for (int k = 0; k < 64; ++k){
            f4 b  = *((const f4*)&Bs[k][tx * 4]);
            f4 a0 = *((const f4*)&As[k][ty * 8]);
            f4 a1 = *((const f4*)&As[k][ty * 8 + 4]);
            #pragma unroll
            for (int i = 0; i < 4; ++i){
                #pragma unroll
                for (int j = 0; j < 4; ++j){
                    acc[i][j]     += a0[i] * b[j];
                    acc[i + 4][j] += a1[i] * b[j];
                }
            }
        }
        __syncthreads();
    }
    f4 bb = ((const f4*)bias)[tx];
    #pragma unroll
    for (int i = 0; i < 8; ++i){
        int r = row0 + ty * 8 + i;
        if (r < M){
            f4 v;
            #pragma unroll
            for (int j = 0; j < 4; ++j){
                float tmp = acc[i][j] + bb[j];
                v[j] = tmp > 0.f ? tmp : 0.f;
            }
            ((f4*)out)[(size_t)r * 32 + tx] = v;
        }
    }
}

extern "C" void kernel_launch(void* const* d_in, const int* in_sizes, int n_in,
                              void* d_out, int out_size, void* d_ws, size_t ws_size,
                              hipStream_t stream) {
    const float* x    = (const float*)d_in[0];
    const float* Wl1  = (const float*)d_in[1];
    const float* bl1  = (const float*)d_in[2];
    const float* Wr1  = (const float*)d_in[3];
    const float* Wl2  = (const float*)d_in[4];
    const float* bl2  = (const float*)d_in[5];
    const float* Wr2  = (const float*)d_in[6];
    const void*  eidx = d_in[7];
    float* out = (float*)d_out;

    const int N  = in_sizes[0] / 128;
    const int E  = in_sizes[7] / 2;
    const int NB = (N + 127) >> 7;          // 128-node coarse buckets (<=1024)

    char* ws = (char*)d_ws;
    size_t off = 0;
    auto alloc = [&](size_t bytes) -> void* {
        void* p = ws + off;
        off += (bytes + 255) & ~(size_t)255;
        return p;
    };
    int*      flag     = (int*)     alloc(4);
    int*      blkhist  = (int*)     alloc((size_t)NB * PB * 4);
    int*      tot      = (int*)     alloc((size_t)NB * 4);
    int*      coff     = (int*)     alloc((size_t)(NB + 1) * 4);
    int*      offs     = (int*)     alloc((size_t)NB * PB * 4);
    uint32_t* bucketed = (uint32_t*)alloc((size_t)E * 4);
    int*      esrc     = (int*)     alloc((size_t)E * 4);
    int*      rowptr   = (int*)     alloc((size_t)(N + 1) * 4);
    float*    agg      = (float*)   alloc((size_t)N * 128 * 4);
    float*    h        = out;       // layer-1 output aliases d_out (safe, see gemm)

    // ---- build dst-sorted CSR (once, reused by both layers) ----
    k_detect    <<<1, 256, 0, stream>>>((const uint32_t*)eidx, flag);
    k_hist      <<<PB, 1024, 0, stream>>>(eidx, E, NB, flag, blkhist);
    k_btot      <<<NB, PB,   0, stream>>>(blkhist, tot);
    k_bscan     <<<1, 1024,  0, stream>>>(tot, NB, coff);
    k_boff      <<<NB, PB,   0, stream>>>(blkhist, coff, offs);
    k_scatter   <<<PB, 1024, 0, stream>>>(eidx, E, NB, flag, offs, bucketed);
    k_bucketsort<<<NB, 1024, 0, stream>>>(bucketed, coff, esrc, rowptr, N, E, NB);

    // ---- layer 1: h = relu(mean_agg(x) @ Wl1 + bl1 + x @ Wr1) ----
    k_aggregate<<<(N + 3) / 4, 256, 0, stream>>>(x, rowptr, esrc, agg, N);
    k_sage_gemm<<<(N + 63) / 64, 256, 0, stream>>>(agg, x, Wl1, Wr1, bl1, h, N);

    // ---- layer 2: out = relu(mean_agg(h) @ Wl2 + bl2 + h @ Wr2) ----
    k_aggregate<<<(N + 3) / 4, 256, 0, stream>>>(h, rowptr, esrc, agg, N);
    k_sage_gemm<<<(N + 63) / 64, 256, 0, stream>>>(agg, h, Wl2, Wr2, bl2, out, N);
}

// Round 10
// 473.176 us; speedup vs baseline: 6.2881x; 1.1717x over previous
//
#include <hip/hip_runtime.h>
#include <cstdint>

typedef float f4 __attribute__((ext_vector_type(4)));
typedef float f2 __attribute__((ext_vector_type(2)));

__device__ inline f4 f4_zero(){ f4 v = {0.f,0.f,0.f,0.f}; return v; }

// bf16 helpers: RNE pack, exact unpack
__device__ inline uint32_t f2bf(float f){
    uint32_t u = __float_as_uint(f);
    return (u + 0x7fffu + ((u >> 16) & 1u)) >> 16;
}
__device__ inline uint32_t pack_bf2(float a, float b){
    return f2bf(a) | (f2bf(b) << 16);
}
__device__ inline f2 bf2_unpack(uint32_t v){
    f2 r;
    r[0] = __uint_as_float(v << 16);
    r[1] = __uint_as_float(v & 0xffff0000u);
    return r;
}

#define PB 256   // blocks for hist/scatter; each (block,bucket) owns a private output range

// ---------- fp32 -> packed bf16 conversion ----------
__global__ __launch_bounds__(256) void k_tobf16(const f4* __restrict__ in,
                                                uint2* __restrict__ out, int n4){
    int i = blockIdx.x * 256 + threadIdx.x;
    if (i >= n4) return;
    f4 v = in[i];
    uint2 o;
    o.x = pack_bf2(v[0], v[1]);
    o.y = pack_bf2(v[2], v[3]);
    out[i] = o;
}

// ---------- detect int64 vs int32 edge_index ----------
__global__ void k_detect(const uint32_t* __restrict__ p, int* __restrict__ flag){
    __shared__ int nz;
    if (threadIdx.x == 0) nz = 0;
    __syncthreads();
    int local = 0;
    for (int i = threadIdx.x; i < 2048; i += blockDim.x)
        if (p[2*i + 1] != 0u) local = 1;
    if (local) atomicOr(&nz, 1);
    __syncthreads();
    if (threadIdx.x == 0) *flag = (nz == 0) ? 1 : 0;   // 1 => int64
}

// ---------- per-block coarse histogram (bucket = dst>>7) ----------
__global__ __launch_bounds__(1024) void k_hist(const void* __restrict__ eidx, int E, int NB,
                                               const int* __restrict__ flag,
                                               int* __restrict__ blkhist){
    __shared__ int lh[1024];
    int t = threadIdx.x, blk = blockIdx.x;
    for (int i = t; i < NB; i += 1024) lh[i] = 0;
    __syncthreads();
    int R = (E + PB - 1) / PB;
    int s = blk * R, e_end = s + R < E ? s + R : E;
    bool is64 = (*flag != 0);
    const uint32_t* p32 = (const uint32_t*)eidx;
    const int*      pi  = (const int*)eidx;
    for (int e = s + t; e < e_end; e += 1024){
        int d = is64 ? (int)p32[2*(size_t)(E + e)] : pi[(size_t)E + e];
        atomicAdd(&lh[d >> 7], 1);
    }
    __syncthreads();
    for (int i = t; i < NB; i += 1024)
        blkhist[(size_t)i * PB + blk] = lh[i];      // block-private slot, no atomic
}

// ---------- per-bucket totals ----------
__global__ __launch_bounds__(PB) void k_btot(const int* __restrict__ blkhist,
                                             int* __restrict__ tot){
    int b = blockIdx.x, t = threadIdx.x, lane = t & 63, w = t >> 6;
    int v = blkhist[(size_t)b * PB + t];
    #pragma unroll
    for (int off = 32; off; off >>= 1) v += __shfl_down(v, off, 64);
    __shared__ int ws[4];
    if (lane == 0) ws[w] = v;
    __syncthreads();
    if (t == 0) tot[b] = ws[0] + ws[1] + ws[2] + ws[3];
}

// ---------- exclusive scan of bucket totals (NB <= 1024) ----------
__global__ __launch_bounds__(1024) void k_bscan(const int* __restrict__ tot, int n,
                                                int* __restrict__ coff){
    int t = threadIdx.x, lane = t & 63, w = t >> 6;
    int v = (t < n) ? tot[t] : 0;
    int x = v;
    #pragma unroll
    for (int off = 1; off < 64; off <<= 1){
        int u = __shfl_up(x, off, 64);
        if (lane >= off) x += u;
    }
    __shared__ int ws[16];
    if (lane == 63) ws[w] = x;
    __syncthreads();
    if (w == 0 && lane < 16){
        int y = ws[lane];
        #pragma unroll
        for (int off = 1; off < 16; off <<= 1){
            int u = __shfl_up(y, off, 64);
            if (lane >= off) y += u;
        }
        ws[lane] = y;
    }
    __syncthreads();
    int incl = x + (w ? ws[w - 1] : 0);
    if (t < n)     coff[t] = incl - v;
    if (t == n - 1) coff[n] = incl;     // == E
}

// ---------- per-(bucket,block) offsets ----------
__global__ __launch_bounds__(PB) void k_boff(const int* __restrict__ blkhist,
                                             const int* __restrict__ coff,
                                             int* __restrict__ offs){
    int b = blockIdx.x, t = threadIdx.x, lane = t & 63, w = t >> 6;
    int h = blkhist[(size_t)b * PB + t];
    int x = h;
    #pragma unroll
    for (int off = 1; off < 64; off <<= 1){
        int u = __shfl_up(x, off, 64);
        if (lane >= off) x += u;
    }
    __shared__ int ws[4];
    if (lane == 63) ws[w] = x;
    __syncthreads();
    int add = 0;
    for (int j = 0; j < w; ++j) add += ws[j];
    offs[(size_t)b * PB + t] = coff[b] + add + x - h;   // exclusive within bucket
}

// ---------- scatter edges into coarse buckets (packed (dst&127)<<17 | src) ----------
__global__ __launch_bounds__(1024) void k_scatter(const void* __restrict__ eidx, int E, int NB,
                                                  const int* __restrict__ flag,
                                                  const int* __restrict__ offs,
                                                  uint32_t* __restrict__ bucketed){
    __shared__ int cur[1024];
    int t = threadIdx.x, blk = blockIdx.x;
    for (int i = t; i < NB; i += 1024) cur[i] = offs[(size_t)i * PB + blk];
    __syncthreads();
    int R = (E + PB - 1) / PB;
    int s = blk * R, e_end = s + R < E ? s + R : E;
    bool is64 = (*flag != 0);
    const uint32_t* p32 = (const uint32_t*)eidx;
    const int*      pi  = (const int*)eidx;
    for (int e = s + t; e < e_end; e += 1024){
        int sv, dv;
        if (is64){ sv = (int)p32[2*(size_t)e]; dv = (int)p32[2*(size_t)(E + e)]; }
        else     { sv = pi[e];                 dv = pi[(size_t)E + e]; }
        int b = dv >> 7;
        int pos = atomicAdd(&cur[b], 1);      // LDS atomic; global range block-private
        bucketed[pos] = ((uint32_t)(dv & 127) << 17) | (uint32_t)sv;
    }
}

// ---------- per-bucket counting sort -> full dst-sorted CSR ----------
__global__ __launch_bounds__(1024) void k_bucketsort(const uint32_t* __restrict__ bucketed,
                                                     const int* __restrict__ coff,
                                                     int* __restrict__ esrc,
                                                     int* __restrict__ rowptr,
                                                     int N, int E, int NB){
    __shared__ int hist[128], cur[128], wtot[2];
    int b = blockIdx.x, t = threadIdx.x;
    if (t < 128) hist[t] = 0;
    __syncthreads();
    int s = coff[b], e_end = coff[b + 1];
    for (int i = s + t; i < e_end; i += 1024)
        atomicAdd(&hist[bucketed[i] >> 17], 1);
    __syncthreads();
    int x = 0, v = 0;
    if (t < 128){
        int lane = t & 63;
        v = hist[t]; x = v;
        #pragma unroll
        for (int off = 1; off < 64; off <<= 1){
            int u = __shfl_up(x, off, 64);
            if (lane >= off) x += u;
        }
        if (lane == 63) wtot[t >> 6] = x;
    }
    __syncthreads();
    if (t < 128){
        int w = t >> 6;
        int excl = x - v + (w ? wtot[0] : 0);     // exclusive within bucket
        int abs0 = s + excl;
        cur[t] = abs0;
        int node = b * 128 + t;
        if (node < N) rowptr[node] = abs0;
    }
    if (b == NB - 1 && t == 0) rowptr[N] = E;
    __syncthreads();
    for (int i = s + t; i < e_end; i += 1024){
        uint32_t val = bucketed[i];
        int r = (int)(val >> 17);
        int pos = atomicAdd(&cur[r], 1);
        esrc[pos] = (int)(val & 0x1FFFFu);
    }
}

// ---------- mean aggregation over bf16 features: one wave per dst node ----------
// Edge indices fetched 64-at-a-time via per-lane vector load, broadcast with
// __shfl; 8 independent gather chains (dest = 1 VGPR each, so ~8 loads in
// flight per wave even at low VGPR budget). Row = 128 bf16 = 256B (lane l
// owns elems 2l,2l+1 as one packed u32). Accumulate fp32, emit packed bf16.
__global__ __launch_bounds__(256) void k_aggregate(const uint32_t* __restrict__ featb,
                                                   const int* __restrict__ rowptr,
                                                   const int* __restrict__ esrc,
                                                   uint32_t* __restrict__ aggb, int N){
    int node = blockIdx.x * 4 + (threadIdx.x >> 6);
    if (node >= N) return;
    int lane = threadIdx.x & 63;
    int b = rowptr[node], e = rowptr[node + 1];
    f2 a0 = {0.f,0.f}, a1 = {0.f,0.f}, a2 = {0.f,0.f}, a3 = {0.f,0.f};
    f2 a4 = {0.f,0.f}, a5 = {0.f,0.f}, a6 = {0.f,0.f}, a7 = {0.f,0.f};
    for (int base = b; base < e; base += 64){
        int m = e - base; if (m > 64) m = 64;
        int idx = (lane < m) ? esrc[base + lane] : 0;   // vector load, 256B/wave
        int j = 0;
        for (; j + 8 <= m; j += 8){
            int s0 = __shfl(idx, j,     64);
            int s1 = __shfl(idx, j + 1, 64);
            int s2 = __shfl(idx, j + 2, 64);
            int s3 = __shfl(idx, j + 3, 64);
            int s4 = __shfl(idx, j + 4, 64);
            int s5 = __shfl(idx, j + 5, 64);
            int s6 = __shfl(idx, j + 6, 64);
            int s7 = __shfl(idx, j + 7, 64);
            uint32_t g0 = featb[(size_t)s0 * 64 + lane];
            uint32_t g1 = featb[(size_t)s1 * 64 + lane];
            uint32_t g2 = featb[(size_t)s2 * 64 + lane];
            uint32_t g3 = featb[(size_t)s3 * 64 + lane];
            uint32_t g4 = featb[(size_t)s4 * 64 + lane];
            uint32_t g5 = featb[(size_t)s5 * 64 + lane];
            uint32_t g6 = featb[(size_t)s6 * 64 + lane];
            uint32_t g7 = featb[(size_t)s7 * 64 + lane];
            a0 += bf2_unpack(g0); a1 += bf2_unpack(g1);
            a2 += bf2_unpack(g2); a3 += bf2_unpack(g3);
            a4 += bf2_unpack(g4); a5 += bf2_unpack(g5);
            a6 += bf2_unpack(g6); a7 += bf2_unpack(g7);
        }
        for (; j < m; ++j){
            int s0 = __shfl(idx, j, 64);
            a0 += bf2_unpack(featb[(size_t)s0 * 64 + lane]);
        }
    }
    f2 acc = ((a0 + a1) + (a2 + a3)) + ((a4 + a5) + (a6 + a7));
    int deg = e - b;
    float scl = 1.0f / (float)(deg > 1 ? deg : 1);
    aggb[(size_t)node * 64 + lane] = pack_bf2(acc[0] * scl, acc[1] * scl);
}

// ---------- fused SAGE linear: out = relu(agg@Wl + bl + X@Wr) ----------
// A1 = agg (bf16 packed). A2 = x/h: fp32 if !A2BF else bf16 packed.
// B/W and all FMA math fp32. Optional fp32 and/or bf16 outputs.
// Aliasing notes: outbf may alias a buffer A2 was read from ONLY if each
// block reads its own 64 rows before its epilogue writes them (holds here).
template<bool A2BF>
__global__ __launch_bounds__(256) void k_sage_gemm(
    const uint32_t* __restrict__ A1b, const void* __restrict__ A2,
    const float* __restrict__ Wl, const float* __restrict__ Wr,
    const float* __restrict__ bias,
    float* __restrict__ outf, uint32_t* __restrict__ outbf, int M)
{
    __shared__ __attribute__((aligned(16))) float Bs[64][128];
    __shared__ __attribute__((aligned(16))) float As[64][64];   // [k][row]
    int tid = threadIdx.x;
    int tx  = tid & 31;
    int ty  = tid >> 5;
    int row0 = blockIdx.x * 64;

    float acc[8][4];
    #pragma unroll
    for (int i = 0; i < 8; ++i)
        #pragma unroll
        for (int j = 0; j < 4; ++j) acc[i][j] = 0.f;

    for (int ch = 0; ch < 4; ++ch){
        const float* Bsrc = (ch < 2) ? Wl : Wr;
        int kOff = (ch & 1) * 64;
        // stage B chunk [64k][128c] : 2048 float4, 8 per thread
        #pragma unroll
        for (int j = 0; j < 8; ++j){
            int f = tid + j * 256;
            int k = f >> 5, c4 = f & 31;
            f4 v = ((const f4*)Bsrc)[(size_t)(kOff + k) * 32 + c4];
            *((f4*)&Bs[k][c4 * 4]) = v;
        }
        // stage A chunk transposed [64k][64row] : 4 elems (1 load) per thread x4
        #pragma unroll
        for (int j = 0; j < 4; ++j){
            int f = tid + j * 256;
            int r = f & 63, kq = f >> 6;      // kq 0..15 -> k = 4kq..4kq+3
            float e0 = 0.f, e1 = 0.f, e2 = 0.f, e3 = 0.f;
            if (row0 + r < M){
                if (ch < 2){
                    uint2 u = ((const uint2*)A1b)[(size_t)(row0 + r) * 32 + (kOff >> 2) + kq];
                    f2 lo = bf2_unpack(u.x), hi = bf2_unpack(u.y);
                    e0 = lo[0]; e1 = lo[1]; e2 = hi[0]; e3 = hi[1];
                } else if (A2BF){
                    uint2 u = ((const uint2*)A2)[(size_t)(row0 + r) * 32 + (kOff >> 2) + kq];
                    f2 lo = bf2_unpack(u.x), hi = bf2_unpack(u.y);
                    e0 = lo[0]; e1 = lo[1]; e2 = hi[0]; e3 = hi[1];
                } else {
                    f4 v = ((const f4*)A2)[(size_t)(row0 + r) * 32 + (kOff >> 2) + kq];
                    e0 = v[0]; e1 = v[1]; e2 = v[2]; e3 = v[3];
                }
            }
            As[kq * 4 + 0][r] = e0;
            As[kq * 4 + 1][r] = e1;
            As[kq * 4 + 2][r] = e2;
            As[kq * 4 + 3][r] = e3;
        }
        __syncthreads();
        #pragma unroll 4
        for (int k = 0; k < 64; ++k){
            f4 b  = *((const f4*)&Bs[k][tx * 4]);
            f4 a0 = *((const f4*)&As[k][ty * 8]);
            f4 a1 = *((const f4*)&As[k][ty * 8 + 4]);
            #pragma unroll
            for (int i = 0; i < 4; ++i){
                #pragma unroll
                for (int j = 0; j < 4; ++j){
                    acc[i][j]     += a0[i] * b[j];
                    acc[i + 4][j] += a1[i] * b[j];
                }
            }
        }
        __syncthreads();
    }
    // epilogue: + bias, relu, store fp32 and/or packed bf16
    f4 bb = ((const f4*)bias)[tx];
    #pragma unroll
    for (int i = 0; i < 8; ++i){
        int r = row0 + ty * 8 + i;
        if (r < M){
            f4 v;
            #pragma unroll
            for (int j = 0; j < 4; ++j){
                float tmp = acc[i][j] + bb[j];
                v[j] = tmp > 0.f ? tmp : 0.f;
            }
            if (outf)
                ((f4*)outf)[(size_t)r * 32 + tx] = v;
            if (outbf){
                uint2 o;
                o.x = pack_bf2(v[0], v[1]);
                o.y = pack_bf2(v[2], v[3]);
                ((uint2*)outbf)[(size_t)r * 32 + tx] = o;
            }
        }
    }
}

extern "C" void kernel_launch(void* const* d_in, const int* in_sizes, int n_in,
                              void* d_out, int out_size, void* d_ws, size_t ws_size,
                              hipStream_t stream) {
    const float* x    = (const float*)d_in[0];
    const float* Wl1  = (const float*)d_in[1];
    const float* bl1  = (const float*)d_in[2];
    const float* Wr1  = (const float*)d_in[3];
    const float* Wl2  = (const float*)d_in[4];
    const float* bl2  = (const float*)d_in[5];
    const float* Wr2  = (const float*)d_in[6];
    const void*  eidx = d_in[7];
    float* out = (float*)d_out;

    const int N  = in_sizes[0] / 128;
    const int E  = in_sizes[7] / 2;
    const int NB = (N + 127) >> 7;          // 128-node coarse buckets (<=1024)

    char* ws = (char*)d_ws;
    size_t off = 0;
    auto alloc = [&](size_t bytes) -> void* {
        void* p = ws + off;
        off += (bytes + 255) & ~(size_t)255;
        return p;
    };
    int*      flag     = (int*)     alloc(4);
    int*      blkhist  = (int*)     alloc((size_t)NB * PB * 4);
    int*      tot      = (int*)     alloc((size_t)NB * 4);
    int*      coff     = (int*)     alloc((size_t)(NB + 1) * 4);
    int*      offs     = (int*)     alloc((size_t)NB * PB * 4);
    int*      esrc     = (int*)     alloc((size_t)E * 4);
    int*      rowptr   = (int*)     alloc((size_t)(N + 1) * 4);
    // unionA: bucketed (E*4, dead after bucketsort) then aggb (N*64*4)
    size_t uA = (size_t)E * 4 > (size_t)N * 256 ? (size_t)E * 4 : (size_t)N * 256;
    uint32_t* unionA   = (uint32_t*)alloc(uA);
    uint32_t* bucketed = unionA;
    uint32_t* aggb     = unionA;
    // unionB: xbf (dead after layer-1 aggregate) then hbf (written by gemm1)
    uint32_t* unionB   = (uint32_t*)alloc((size_t)N * 256);
    uint32_t* xbf      = unionB;
    uint32_t* hbf      = unionB;

    // ---- bf16 feature table + dst-sorted CSR (reused by both layers) ----
    k_tobf16    <<<(N * 32 + 255) / 256, 256, 0, stream>>>((const f4*)x, (uint2*)xbf, N * 32);
    k_detect    <<<1, 256, 0, stream>>>((const uint32_t*)eidx, flag);
    k_hist      <<<PB, 1024, 0, stream>>>(eidx, E, NB, flag, blkhist);
    k_btot      <<<NB, PB,   0, stream>>>(blkhist, tot);
    k_bscan     <<<1, 1024,  0, stream>>>(tot, NB, coff);
    k_boff      <<<NB, PB,   0, stream>>>(blkhist, coff, offs);
    k_scatter   <<<PB, 1024, 0, stream>>>(eidx, E, NB, flag, offs, bucketed);
    k_bucketsort<<<NB, 1024, 0, stream>>>(bucketed, coff, esrc, rowptr, N, E, NB);

    // ---- layer 1: h = relu(mean_agg(x) @ Wl1 + bl1 + x @ Wr1) ----
    k_aggregate<<<(N + 3) / 4, 256, 0, stream>>>(xbf, rowptr, esrc, aggb, N);
    k_sage_gemm<false><<<(N + 63) / 64, 256, 0, stream>>>(
        aggb, (const void*)x, Wl1, Wr1, bl1, nullptr, hbf, N);

    // ---- layer 2: out = relu(mean_agg(h) @ Wl2 + bl2 + h @ Wr2) ----
    k_aggregate<<<(N + 3) / 4, 256, 0, stream>>>(hbf, rowptr, esrc, aggb, N);
    k_sage_gemm<true><<<(N + 63) / 64, 256, 0, stream>>>(
        aggb, (const void*)hbf, Wl2, Wr2, bl2, out, nullptr, N);
}

// Round 11
// 356.111 us; speedup vs baseline: 8.3551x; 1.3287x over previous
//
#include <hip/hip_runtime.h>
#include <cstdint>

typedef float f4 __attribute__((ext_vector_type(4)));
typedef float f2 __attribute__((ext_vector_type(2)));
typedef short bfv8 __attribute__((ext_vector_type(8)));   // 8 bf16 = 4 VGPR

__device__ inline f4 f4_zero(){ f4 v = {0.f,0.f,0.f,0.f}; return v; }

// bf16 helpers: RNE pack, exact unpack
__device__ inline uint32_t f2bf(float f){
    uint32_t u = __float_as_uint(f);
    return (u + 0x7fffu + ((u >> 16) & 1u)) >> 16;
}
__device__ inline uint32_t pack_bf2(float a, float b){
    return f2bf(a) | (f2bf(b) << 16);
}
__device__ inline f2 bf2_unpack(uint32_t v){
    f2 r;
    r[0] = __uint_as_float(v << 16);
    r[1] = __uint_as_float(v & 0xffff0000u);
    return r;
}

#define PB 256   // blocks for hist/scatter; each (block,bucket) owns a private output range

// ---------- fp32 -> packed bf16 conversion ----------
__global__ __launch_bounds__(256) void k_tobf16(const f4* __restrict__ in,
                                                uint2* __restrict__ out, int n4){
    int i = blockIdx.x * 256 + threadIdx.x;
    if (i >= n4) return;
    f4 v = in[i];
    uint2 o;
    o.x = pack_bf2(v[0], v[1]);
    o.y = pack_bf2(v[2], v[3]);
    out[i] = o;
}

// ---------- detect int64 vs int32 edge_index ----------
__global__ void k_detect(const uint32_t* __restrict__ p, int* __restrict__ flag){
    __shared__ int nz;
    if (threadIdx.x == 0) nz = 0;
    __syncthreads();
    int local = 0;
    for (int i = threadIdx.x; i < 2048; i += blockDim.x)
        if (p[2*i + 1] != 0u) local = 1;
    if (local) atomicOr(&nz, 1);
    __syncthreads();
    if (threadIdx.x == 0) *flag = (nz == 0) ? 1 : 0;   // 1 => int64
}

// ---------- per-block coarse histogram (bucket = dst>>7) ----------
__global__ __launch_bounds__(1024) void k_hist(const void* __restrict__ eidx, int E, int NB,
                                               const int* __restrict__ flag,
                                               int* __restrict__ blkhist){
    __shared__ int lh[1024];
    int t = threadIdx.x, blk = blockIdx.x;
    for (int i = t; i < NB; i += 1024) lh[i] = 0;
    __syncthreads();
    int R = (E + PB - 1) / PB;
    int s = blk * R, e_end = s + R < E ? s + R : E;
    bool is64 = (*flag != 0);
    const uint32_t* p32 = (const uint32_t*)eidx;
    const int*      pi  = (const int*)eidx;
    for (int e = s + t; e < e_end; e += 1024){
        int d = is64 ? (int)p32[2*(size_t)(E + e)] : pi[(size_t)E + e];
        atomicAdd(&lh[d >> 7], 1);
    }
    __syncthreads();
    for (int i = t; i < NB; i += 1024)
        blkhist[(size_t)i * PB + blk] = lh[i];      // block-private slot, no atomic
}

// ---------- per-bucket totals ----------
__global__ __launch_bounds__(PB) void k_btot(const int* __restrict__ blkhist,
                                             int* __restrict__ tot){
    int b = blockIdx.x, t = threadIdx.x, lane = t & 63, w = t >> 6;
    int v = blkhist[(size_t)b * PB + t];
    #pragma unroll
    for (int off = 32; off; off >>= 1) v += __shfl_down(v, off, 64);
    __shared__ int ws[4];
    if (lane == 0) ws[w] = v;
    __syncthreads();
    if (t == 0) tot[b] = ws[0] + ws[1] + ws[2] + ws[3];
}

// ---------- exclusive scan of bucket totals (NB <= 1024) ----------
__global__ __launch_bounds__(1024) void k_bscan(const int* __restrict__ tot, int n,
                                                int* __restrict__ coff){
    int t = threadIdx.x, lane = t & 63, w = t >> 6;
    int v = (t < n) ? tot[t] : 0;
    int x = v;
    #pragma unroll
    for (int off = 1; off < 64; off <<= 1){
        int u = __shfl_up(x, off, 64);
        if (lane >= off) x += u;
    }
    __shared__ int ws[16];
    if (lane == 63) ws[w] = x;
    __syncthreads();
    if (w == 0 && lane < 16){
        int y = ws[lane];
        #pragma unroll
        for (int off = 1; off < 16; off <<= 1){
            int u = __shfl_up(y, off, 64);
            if (lane >= off) y += u;
        }
        ws[lane] = y;
    }
    __syncthreads();
    int incl = x + (w ? ws[w - 1] : 0);
    if (t < n)     coff[t] = incl - v;
    if (t == n - 1) coff[n] = incl;     // == E
}

// ---------- per-(bucket,block) offsets ----------
__global__ __launch_bounds__(PB) void k_boff(const int* __restrict__ blkhist,
                                             const int* __restrict__ coff,
                                             int* __restrict__ offs){
    int b = blockIdx.x, t = threadIdx.x, lane = t & 63, w = t >> 6;
    int h = blkhist[(size_t)b * PB + t];
    int x = h;
    #pragma unroll
    for (int off = 1; off < 64; off <<= 1){
        int u = __shfl_up(x, off, 64);
        if (lane >= off) x += u;
    }
    __shared__ int ws[4];
    if (lane == 63) ws[w] = x;
    __syncthreads();
    int add = 0;
    for (int j = 0; j < w; ++j) add += ws[j];
    offs[(size_t)b * PB + t] = coff[b] + add + x - h;   // exclusive within bucket
}

// ---------- scatter edges into coarse buckets (packed (dst&127)<<17 | src) ----------
__global__ __launch_bounds__(1024) void k_scatter(const void* __restrict__ eidx, int E, int NB,
                                                  const int* __restrict__ flag,
                                                  const int* __restrict__ offs,
                                                  uint32_t* __restrict__ bucketed){
    __shared__ int cur[1024];
    int t = threadIdx.x, blk = blockIdx.x;
    for (int i = t; i < NB; i += 1024) cur[i] = offs[(size_t)i * PB + blk];
    __syncthreads();
    int R = (E + PB - 1) / PB;
    int s = blk * R, e_end = s + R < E ? s + R : E;
    bool is64 = (*flag != 0);
    const uint32_t* p32 = (const uint32_t*)eidx;
    const int*      pi  = (const int*)eidx;
    for (int e = s + t; e < e_end; e += 1024){
        int sv, dv;
        if (is64){ sv = (int)p32[2*(size_t)e]; dv = (int)p32[2*(size_t)(E + e)]; }
        else     { sv = pi[e];                 dv = pi[(size_t)E + e]; }
        int b = dv >> 7;
        int pos = atomicAdd(&cur[b], 1);      // LDS atomic; global range block-private
        bucketed[pos] = ((uint32_t)(dv & 127) << 17) | (uint32_t)sv;
    }
}

// ---------- per-bucket counting sort -> full dst-sorted CSR ----------
__global__ __launch_bounds__(1024) void k_bucketsort(const uint32_t* __restrict__ bucketed,
                                                     const int* __restrict__ coff,
                                                     int* __restrict__ esrc,
                                                     int* __restrict__ rowptr,
                                                     int N, int E, int NB){
    __shared__ int hist[128], cur[128], wtot[2];
    int b = blockIdx.x, t = threadIdx.x;
    if (t < 128) hist[t] = 0;
    __syncthreads();
    int s = coff[b], e_end = coff[b + 1];
    for (int i = s + t; i < e_end; i += 1024)
        atomicAdd(&hist[bucketed[i] >> 17], 1);
    __syncthreads();
    int x = 0, v = 0;
    if (t < 128){
        int lane = t & 63;
        v = hist[t]; x = v;
        #pragma unroll
        for (int off = 1; off < 64; off <<= 1){
            int u = __shfl_up(x, off, 64);
            if (lane >= off) x += u;
        }
        if (lane == 63) wtot[t >> 6] = x;
    }
    __syncthreads();
    if (t < 128){
        int w = t >> 6;
        int excl = x - v + (w ? wtot[0] : 0);     // exclusive within bucket
        int abs0 = s + excl;
        cur[t] = abs0;
        int node = b * 128 + t;
        if (node < N) rowptr[node] = abs0;
    }
    if (b == NB - 1 && t == 0) rowptr[N] = E;
    __syncthreads();
    for (int i = s + t; i < e_end; i += 1024){
        uint32_t val = bucketed[i];
        int r = (int)(val >> 17);
        int pos = atomicAdd(&cur[r], 1);
        esrc[pos] = (int)(val & 0x1FFFFu);
    }
}

// ---------- mean aggregation over bf16 features: one wave per dst node ----------
__global__ __launch_bounds__(256) void k_aggregate(const uint32_t* __restrict__ featb,
                                                   const int* __restrict__ rowptr,
                                                   const int* __restrict__ esrc,
                                                   uint32_t* __restrict__ aggb, int N){
    int node = blockIdx.x * 4 + (threadIdx.x >> 6);
    if (node >= N) return;
    int lane = threadIdx.x & 63;
    int b = rowptr[node], e = rowptr[node + 1];
    f2 a0 = {0.f,0.f}, a1 = {0.f,0.f}, a2 = {0.f,0.f}, a3 = {0.f,0.f};
    f2 a4 = {0.f,0.f}, a5 = {0.f,0.f}, a6 = {0.f,0.f}, a7 = {0.f,0.f};
    for (int base = b; base < e; base += 64){
        int m = e - base; if (m > 64) m = 64;
        int idx = (lane < m) ? esrc[base + lane] : 0;   // vector load, 256B/wave
        int j = 0;
        for (; j + 8 <= m; j += 8){
            int s0 = __shfl(idx, j,     64);
            int s1 = __shfl(idx, j + 1, 64);
            int s2 = __shfl(idx, j + 2, 64);
            int s3 = __shfl(idx, j + 3, 64);
            int s4 = __shfl(idx, j + 4, 64);
            int s5 = __shfl(idx, j + 5, 64);
            int s6 = __shfl(idx, j + 6, 64);
            int s7 = __shfl(idx, j + 7, 64);
            uint32_t g0 = featb[(size_t)s0 * 64 + lane];
            uint32_t g1 = featb[(size_t)s1 * 64 + lane];
            uint32_t g2 = featb[(size_t)s2 * 64 + lane];
            uint32_t g3 = featb[(size_t)s3 * 64 + lane];
            uint32_t g4 = featb[(size_t)s4 * 64 + lane];
            uint32_t g5 = featb[(size_t)s5 * 64 + lane];
            uint32_t g6 = featb[(size_t)s6 * 64 + lane];
            uint32_t g7 = featb[(size_t)s7 * 64 + lane];
            a0 += bf2_unpack(g0); a1 += bf2_unpack(g1);
            a2 += bf2_unpack(g2); a3 += bf2_unpack(g3);
            a4 += bf2_unpack(g4); a5 += bf2_unpack(g5);
            a6 += bf2_unpack(g6); a7 += bf2_unpack(g7);
        }
        for (; j < m; ++j){
            int s0 = __shfl(idx, j, 64);
            a0 += bf2_unpack(featb[(size_t)s0 * 64 + lane]);
        }
    }
    f2 acc = ((a0 + a1) + (a2 + a3)) + ((a4 + a5) + (a6 + a7));
    int deg = e - b;
    float scl = 1.0f / (float)(deg > 1 ? deg : 1);
    aggb[(size_t)node * 64 + lane] = pack_bf2(acc[0] * scl, acc[1] * scl);
}

// ---------- weight prep: [Wl;Wr] fp32 -> bf16, MFMA-b_frag-swizzled ----------
// Bsw 16B entry index ((s*8 + ct)*64 + l) holds W[s*32 + (l>>4)*8 + j][ct*16 + (l&15)],
// j = 0..7, where W[k][c] = k<128 ? Wl[k][c] : Wr[k-128][c].  4096 threads total.
__global__ __launch_bounds__(256) void k_wprep(const float* __restrict__ Wl,
                                               const float* __restrict__ Wr,
                                               uint32_t* __restrict__ Bsw){
    int t = blockIdx.x * 256 + threadIdx.x;   // 0..4095
    int s = t >> 9, ct = (t >> 6) & 7, l = t & 63;
    int k0 = s * 32 + (l >> 4) * 8;
    int c  = ct * 16 + (l & 15);
    unsigned short e[8];
    #pragma unroll
    for (int j = 0; j < 8; ++j){
        int k = k0 + j;
        float v = (k < 128) ? Wl[(size_t)k * 128 + c] : Wr[(size_t)(k - 128) * 128 + c];
        e[j] = (unsigned short)f2bf(v);
    }
    uint32_t* o = Bsw + (size_t)t * 4;
    o[0] = (uint32_t)e[0] | ((uint32_t)e[1] << 16);
    o[1] = (uint32_t)e[2] | ((uint32_t)e[3] << 16);
    o[2] = (uint32_t)e[4] | ((uint32_t)e[5] << 16);
    o[3] = (uint32_t)e[6] | ((uint32_t)e[7] << 16);
}

// ---------- MFMA SAGE linear: out = relu([A1|A2] @ Bsw + bias) ----------
// LDS-free: a_frag = 16B contiguous load from the bf16 row; b_frag = coalesced
// 1KB/wave load from the pre-swizzled Bsw (L2-hot, 64KB). K=256 fully unrolled:
// 8 k-steps x (1 a-load + 8 b-loads + 8 MFMA). C/D mapping (m89-verified):
// col = lane&15, row = (lane>>4)*4 + reg. Rows are wave-private, so
// outbf may alias A2b (layer 1: xbf==hbf) — acc depends on all A2 loads,
// stores follow. OOB waves clamp loads to row M-1 and store nothing.
__global__ __launch_bounds__(256) void k_sage_mfma(
    const uint32_t* __restrict__ A1b, const uint32_t* __restrict__ A2b,
    const uint32_t* __restrict__ Bsw, const float* __restrict__ bias,
    float* __restrict__ outf, uint32_t* __restrict__ outbf, int M)
{
    int tid = threadIdx.x;
    int w = tid >> 6, l = tid & 63;
    int l15 = l & 15, l4 = l >> 4;
    int row = blockIdx.x * 64 + w * 16 + l15;
    int rowc = row < M ? row : M - 1;
    const char* a1p = (const char*)(A1b + (size_t)rowc * 64) + l4 * 16;
    const char* a2p = (const char*)(A2b + (size_t)rowc * 64) + l4 * 16;
    const char* bp  = (const char*)Bsw + (size_t)l * 16;

    f4 acc[8];
    #pragma unroll
    for (int ct = 0; ct < 8; ++ct) acc[ct] = f4_zero();

    #pragma unroll
    for (int s = 0; s < 8; ++s){
        bfv8 a = *(const bfv8*)((s < 4 ? a1p : a2p) + (s & 3) * 64);
        #pragma unroll
        for (int ct = 0; ct < 8; ++ct){
            bfv8 b = *(const bfv8*)(bp + (size_t)(s * 8 + ct) * 1024);
            acc[ct] = __builtin_amdgcn_mfma_f32_16x16x32_bf16(a, b, acc[ct], 0, 0, 0);
        }
    }

    int orow0 = blockIdx.x * 64 + w * 16 + l4 * 4;
    #pragma unroll
    for (int ct = 0; ct < 8; ++ct){
        int col = ct * 16 + l15;
        float bb = bias[col];
        #pragma unroll
        for (int r = 0; r < 4; ++r){
            int orow = orow0 + r;
            if (orow < M){
                float v = acc[ct][r] + bb;
                v = v > 0.f ? v : 0.f;
                if (outf)  outf[(size_t)orow * 128 + col] = v;
                if (outbf) ((unsigned short*)outbf)[(size_t)orow * 128 + col] =
                               (unsigned short)f2bf(v);
            }
        }
    }
}

extern "C" void kernel_launch(void* const* d_in, const int* in_sizes, int n_in,
                              void* d_out, int out_size, void* d_ws, size_t ws_size,
                              hipStream_t stream) {
    const float* x    = (const float*)d_in[0];
    const float* Wl1  = (const float*)d_in[1];
    const float* bl1  = (const float*)d_in[2];
    const float* Wr1  = (const float*)d_in[3];
    const float* Wl2  = (const float*)d_in[4];
    const float* bl2  = (const float*)d_in[5];
    const float* Wr2  = (const float*)d_in[6];
    const void*  eidx = d_in[7];
    float* out = (float*)d_out;

    const int N  = in_sizes[0] / 128;
    const int E  = in_sizes[7] / 2;
    const int NB = (N + 127) >> 7;          // 128-node coarse buckets (<=1024)

    char* ws = (char*)d_ws;
    size_t off = 0;
    auto alloc = [&](size_t bytes) -> void* {
        void* p = ws + off;
        off += (bytes + 255) & ~(size_t)255;
        return p;
    };
    int*      flag     = (int*)     alloc(4);
    int*      blkhist  = (int*)     alloc((size_t)NB * PB * 4);
    int*      tot      = (int*)     alloc((size_t)NB * 4);
    int*      coff     = (int*)     alloc((size_t)(NB + 1) * 4);
    int*      offs     = (int*)     alloc((size_t)NB * PB * 4);
    int*      esrc     = (int*)     alloc((size_t)E * 4);
    int*      rowptr   = (int*)     alloc((size_t)(N + 1) * 4);
    uint32_t* bsw1     = (uint32_t*)alloc(65536);
    uint32_t* bsw2     = (uint32_t*)alloc(65536);
    // unionA: bucketed (E*4, dead after bucketsort) then aggb (N*64*4)
    size_t uA = (size_t)E * 4 > (size_t)N * 256 ? (size_t)E * 4 : (size_t)N * 256;
    uint32_t* unionA   = (uint32_t*)alloc(uA);
    uint32_t* bucketed = unionA;
    uint32_t* aggb     = unionA;
    // unionB: xbf (dead after layer-1 gemm reads it) then hbf (written by gemm1)
    uint32_t* unionB   = (uint32_t*)alloc((size_t)N * 256);
    uint32_t* xbf      = unionB;
    uint32_t* hbf      = unionB;

    const int GB = (N + 63) / 64;           // gemm blocks

    // ---- bf16 feature table + swizzled weights + dst-sorted CSR ----
    k_tobf16    <<<(N * 32 + 255) / 256, 256, 0, stream>>>((const f4*)x, (uint2*)xbf, N * 32);
    k_wprep     <<<16, 256, 0, stream>>>(Wl1, Wr1, bsw1);
    k_wprep     <<<16, 256, 0, stream>>>(Wl2, Wr2, bsw2);
    k_detect    <<<1, 256, 0, stream>>>((const uint32_t*)eidx, flag);
    k_hist      <<<PB, 1024, 0, stream>>>(eidx, E, NB, flag, blkhist);
    k_btot      <<<NB, PB,   0, stream>>>(blkhist, tot);
    k_bscan     <<<1, 1024,  0, stream>>>(tot, NB, coff);
    k_boff      <<<NB, PB,   0, stream>>>(blkhist, coff, offs);
    k_scatter   <<<PB, 1024, 0, stream>>>(eidx, E, NB, flag, offs, bucketed);
    k_bucketsort<<<NB, 1024, 0, stream>>>(bucketed, coff, esrc, rowptr, N, E, NB);

    // ---- layer 1: h = relu(mean_agg(x) @ Wl1 + bl1 + x @ Wr1) ----
    k_aggregate<<<(N + 3) / 4, 256, 0, stream>>>(xbf, rowptr, esrc, aggb, N);
    k_sage_mfma<<<GB, 256, 0, stream>>>(aggb, xbf, bsw1, bl1, nullptr, hbf, N);

    // ---- layer 2: out = relu(mean_agg(h) @ Wl2 + bl2 + h @ Wr2) ----
    k_aggregate<<<(N + 3) / 4, 256, 0, stream>>>(hbf, rowptr, esrc, aggb, N);
    k_sage_mfma<<<GB, 256, 0, stream>>>(aggb, hbf, bsw2, bl2, out, nullptr, N);
}